// Round 1
// baseline (5525.466 us; speedup 1.0000x reference)
//
#include <hip/hip_runtime.h>

typedef short bf16x8 __attribute__((ext_vector_type(8)));
typedef float f32x4 __attribute__((ext_vector_type(4)));

#define HID   1024
#define BATCH 8
#define TLEN  256
#define VOCABN 50257
#define GATES 4096   // 4*HID
#define M_ROWS 2048  // B*T

__device__ __forceinline__ unsigned short f2bf(float x) {
  unsigned int u = __float_as_uint(x);
  unsigned int r = (u + 0x7fffu + ((u >> 16) & 1u)) >> 16;
  return (unsigned short)r;
}

__global__ void conv_f32_bf16(const float* __restrict__ src,
                              unsigned short* __restrict__ dst, int n4) {
  int i = blockIdx.x * 256 + threadIdx.x;
  if (i >= n4) return;
  float4 v = ((const float4*)src)[i];
  ushort4 o;
  o.x = f2bf(v.x); o.y = f2bf(v.y); o.z = f2bf(v.z); o.w = f2bf(v.w);
  ((ushort4*)dst)[i] = o;
}

__global__ void bias_sum_kernel(const float* __restrict__ a,
                                const float* __restrict__ b,
                                float* __restrict__ o) {
  int i = blockIdx.x * 256 + threadIdx.x;
  if (i < GATES) o[i] = a[i] + b[i];
}

// C[m][n] = sum_k A[m,k]*B[n,k] + bias[n].  A,B bf16 K-major, C fp32.
// tokens!=nullptr => A row m is table row tokens[m] (embedding gather).
#define GSTR 72  // LDS row stride in bf16 (64 data + 8 pad) -> conflict-free b128 frag reads

__global__ __launch_bounds__(256) void gemm_bt_bf16(
    const unsigned short* __restrict__ A, const unsigned short* __restrict__ Bm,
    const float* __restrict__ bias, float* __restrict__ C,
    const int* __restrict__ tokens, int ldc, int Nreal) {
  __shared__ unsigned short As[128 * GSTR];
  __shared__ unsigned short Bs[128 * GSTR];
  const int tid = threadIdx.x;
  const int m0 = blockIdx.x * 128;
  const int n0 = blockIdx.y * 128;
  const int wid = tid >> 6, lane = tid & 63;
  const int wm = (wid & 1) * 64, wn = (wid >> 1) * 64;
  const int lm = lane & 15, quad = lane >> 4;

  f32x4 acc[4][4];
  #pragma unroll
  for (int i = 0; i < 4; ++i)
    #pragma unroll
    for (int j = 0; j < 4; ++j) acc[i][j] = (f32x4){0.f, 0.f, 0.f, 0.f};

  for (int k0 = 0; k0 < HID; k0 += 64) {
    #pragma unroll
    for (int it = 0; it < 4; ++it) {           // 1024 16B-chunks per tile, 256 thr
      int c = tid + it * 256;
      int row = c >> 3, ch = c & 7;
      int gm = m0 + row;
      int arow = tokens ? tokens[gm] : gm;
      uint4 v = *(const uint4*)(A + (size_t)arow * HID + k0 + ch * 8);
      *(uint4*)&As[row * GSTR + ch * 8] = v;
      int gn = n0 + row;
      uint4 w = make_uint4(0u, 0u, 0u, 0u);
      if (gn < Nreal) w = *(const uint4*)(Bm + (size_t)gn * HID + k0 + ch * 8);
      *(uint4*)&Bs[row * GSTR + ch * 8] = w;
    }
    __syncthreads();
    #pragma unroll
    for (int kk = 0; kk < 2; ++kk) {
      bf16x8 af[4], bfr[4];
      #pragma unroll
      for (int i = 0; i < 4; ++i)
        af[i] = *(const bf16x8*)&As[(wm + i * 16 + lm) * GSTR + kk * 32 + quad * 8];
      #pragma unroll
      for (int j = 0; j < 4; ++j)
        bfr[j] = *(const bf16x8*)&Bs[(wn + j * 16 + lm) * GSTR + kk * 32 + quad * 8];
      #pragma unroll
      for (int i = 0; i < 4; ++i)
        #pragma unroll
        for (int j = 0; j < 4; ++j)
          acc[i][j] = __builtin_amdgcn_mfma_f32_16x16x32_bf16(af[i], bfr[j], acc[i][j], 0, 0, 0);
    }
    __syncthreads();
  }
  // D layout: col = lane&15, row = quad*4 + reg  [measured m89/m91]
  #pragma unroll
  for (int i = 0; i < 4; ++i) {
    #pragma unroll
    for (int j = 0; j < 4; ++j) {
      #pragma unroll
      for (int r = 0; r < 4; ++r) {
        int gm = m0 + wm + i * 16 + quad * 4 + r;
        int gn = n0 + wn + j * 16 + lm;
        if (gn < Nreal)
          C[(size_t)gm * ldc + gn] = acc[i][j][r] + (bias ? bias[gn] : 0.f);
      }
    }
  }
}

// One LSTM timestep. grid=256 blocks (4 cells each), 128 threads.
// fp32 everywhere; h ping-pong in ws; c owned per-block (no race).
__global__ __launch_bounds__(128) void lstm_step(
    const float* __restrict__ whh, const float* __restrict__ xproj,
    float* __restrict__ hbuf, float* __restrict__ cbuf,
    unsigned short* __restrict__ adec, float* __restrict__ out_hc, int t) {
  __shared__ float hs[BATCH][HID + 4];   // +4 pad: b-rows spread banks
  __shared__ float gates[16][8];
  const int tid = threadIdx.x;
  const int j0 = blockIdx.x * 4;

  const float4* hsrc = (const float4*)(hbuf + (size_t)(t & 1) * (BATCH * HID));
  for (int i = tid; i < BATCH * HID / 4; i += 128) {
    float4 v;
    if (t == 0) v = make_float4(0.f, 0.f, 0.f, 0.f);
    else        v = hsrc[i];
    int b = i >> 8;
    int k = (i & 255) * 4;
    *(float4*)&hs[b][k] = v;
  }
  __syncthreads();

  const int r = tid >> 3;          // 0..15 : cell-local (r>>2) x gate (r&3)
  const int b = tid & 7;
  const int gate = r & 3, cl = r >> 2;
  const int grow = gate * HID + j0 + cl;
  const float4* wr = (const float4*)(whh + (size_t)grow * HID);
  float a0 = 0.f, a1 = 0.f, a2 = 0.f, a3 = 0.f;
  #pragma unroll 2
  for (int kk = 0; kk < 64; ++kk) {
    float4 w0 = wr[kk * 4 + 0], w1 = wr[kk * 4 + 1];
    float4 w2 = wr[kk * 4 + 2], w3 = wr[kk * 4 + 3];
    const float* hp = &hs[b][kk * 16];
    float4 h0 = *(const float4*)(hp);
    float4 h1 = *(const float4*)(hp + 4);
    float4 h2 = *(const float4*)(hp + 8);
    float4 h3 = *(const float4*)(hp + 12);
    a0 += w0.x * h0.x + w0.y * h0.y + w0.z * h0.z + w0.w * h0.w;
    a1 += w1.x * h1.x + w1.y * h1.y + w1.z * h1.z + w1.w * h1.w;
    a2 += w2.x * h2.x + w2.y * h2.y + w2.z * h2.z + w2.w * h2.w;
    a3 += w3.x * h3.x + w3.y * h3.y + w3.z * h3.z + w3.w * h3.w;
  }
  float acc = (a0 + a1) + (a2 + a3);
  acc += xproj[(size_t)(b * TLEN + t) * GATES + grow];
  gates[r][b] = acc;
  __syncthreads();

  if (tid < 32) {
    int cl2 = tid >> 3, bb = tid & 7;
    int j = j0 + cl2;
    float gi = gates[cl2 * 4 + 0][bb];
    float gf = gates[cl2 * 4 + 1][bb];
    float gg = gates[cl2 * 4 + 2][bb];
    float go = gates[cl2 * 4 + 3][bb];
    float si = 1.f / (1.f + __expf(-gi));
    float sf = 1.f / (1.f + __expf(-gf));
    float tg = tanhf(gg);
    float so = 1.f / (1.f + __expf(-go));
    float cp = (t == 0) ? 0.f : cbuf[bb * HID + j];
    float c = sf * cp + si * tg;
    float h = so * tanhf(c);
    cbuf[bb * HID + j] = c;
    hbuf[(size_t)((t + 1) & 1) * (BATCH * HID) + bb * HID + j] = h;
    adec[(size_t)(bb * TLEN + t) * HID + j] = f2bf(h);
    if (t == TLEN - 1) {
      out_hc[bb * HID + j] = h;                  // hT
      out_hc[BATCH * HID + bb * HID + j] = c;    // cT
    }
  }
}

// In-place log-softmax over rows of [2048][50257]
__global__ __launch_bounds__(512) void logsoftmax_rows(float* __restrict__ data) {
  const int row = blockIdx.x;
  float* p = data + (size_t)row * VOCABN;
  const int tid = threadIdx.x;
  float m = -INFINITY, l = 0.f;
  for (int i = tid; i < VOCABN; i += 512) {
    float x = p[i];
    float nm = fmaxf(m, x);
    l = l * __expf(m - nm) + __expf(x - nm);
    m = nm;
  }
  #pragma unroll
  for (int off = 32; off > 0; off >>= 1) {
    float m2 = __shfl_down(m, off);
    float l2 = __shfl_down(l, off);
    float nm = fmaxf(m, m2);
    l = l * __expf(m - nm) + l2 * __expf(m2 - nm);
    m = nm;
  }
  __shared__ float sm[8], sl[8];
  if ((tid & 63) == 0) { sm[tid >> 6] = m; sl[tid >> 6] = l; }
  __syncthreads();
  if (tid == 0) {
    m = sm[0]; l = sl[0];
    for (int i2 = 1; i2 < 8; ++i2) {
      float m2 = sm[i2], l2 = sl[i2];
      float nm = fmaxf(m, m2);
      l = l * __expf(m - nm) + l2 * __expf(m2 - nm);
      m = nm;
    }
    sm[0] = m; sl[0] = logf(l);
  }
  __syncthreads();
  float M = sm[0], L = sl[0];
  for (int i = tid; i < VOCABN; i += 512) p[i] = p[i] - M - L;
}

extern "C" void kernel_launch(void* const* d_in, const int* in_sizes, int n_in,
                              void* d_out, int out_size, void* d_ws, size_t ws_size,
                              hipStream_t stream) {
  const int*   x     = (const int*)d_in[0];
  const float* embW  = (const float*)d_in[1];
  const float* w_ih  = (const float*)d_in[2];
  const float* w_hh  = (const float*)d_in[3];
  const float* b_ih  = (const float*)d_in[4];
  const float* b_hh  = (const float*)d_in[5];
  const float* dec_b = (const float*)d_in[6];
  float* out = (float*)d_out;

  // ws carve (~142.3 MB total)
  char* ws = (char*)d_ws;
  unsigned short* emb_bf = (unsigned short*)ws;  ws += (size_t)VOCABN * HID * 2;
  unsigned short* wih_bf = (unsigned short*)ws;  ws += (size_t)GATES * HID * 2;
  float* bias_s = (float*)ws;                    ws += (size_t)GATES * 4;
  float* xproj  = (float*)ws;                    ws += (size_t)M_ROWS * GATES * 4;
  unsigned short* adec = (unsigned short*)ws;    ws += (size_t)M_ROWS * HID * 2;
  float* hbuf = (float*)ws;                      ws += (size_t)2 * BATCH * HID * 4;
  float* cbuf = (float*)ws;                      ws += (size_t)BATCH * HID * 4;

  int n4emb = VOCABN * HID / 4;
  conv_f32_bf16<<<(n4emb + 255) / 256, 256, 0, stream>>>(embW, emb_bf, n4emb);
  int n4wih = GATES * HID / 4;
  conv_f32_bf16<<<(n4wih + 255) / 256, 256, 0, stream>>>(w_ih, wih_bf, n4wih);
  bias_sum_kernel<<<16, 256, 0, stream>>>(b_ih, b_hh, bias_s);

  // x_proj[bt][g] = emb_W[x[bt]] . w_ih[g] + (b_ih+b_hh)[g]
  gemm_bt_bf16<<<dim3(16, 32), 256, 0, stream>>>(emb_bf, wih_bf, bias_s, xproj,
                                                 x, GATES, GATES);

  for (int t = 0; t < TLEN; ++t)
    lstm_step<<<256, 128, 0, stream>>>(w_hh, xproj, hbuf, cbuf, adec,
                                       out + (size_t)M_ROWS * VOCABN, t);

  // logits[bt][v] = h[bt] . emb_W[v] + dec_b[v]
  gemm_bt_bf16<<<dim3(16, 393), 256, 0, stream>>>(adec, emb_bf, dec_b, out,
                                                  nullptr, VOCABN, VOCABN);

  logsoftmax_rows<<<2048, 512, 0, stream>>>(out);
}